// Round 11
// baseline (3606.965 us; speedup 1.0000x reference)
//
#include <hip/hip_runtime.h>
#include <hip/hip_bf16.h>

#define BATCH 32
#define SEQ   512
#define IND   1024
#define HD    1024
#define ZD    2048   // IN + H
#define NG    4096   // 4*H
#define WG_ELEMS (1024 * 2048)   // elements per gate weight matrix
#define PBLK 128                 // consumer grid size (producers: PBLK..2*PBLK)
#define FSTR 68                  // flag slot stride in u32 (272B: stripes channels)

typedef short  shortx8 __attribute__((ext_vector_type(8)));
typedef float  floatx4 __attribute__((ext_vector_type(4)));

#define MFMA16(a, b, c) __builtin_amdgcn_mfma_f32_16x16x32_bf16((a), (b), (c), 0, 0, 0)

__device__ __forceinline__ float sigmoidf_(float x) {
    return 1.0f / (1.0f + __expf(-x));
}
__device__ __forceinline__ float tanhf_(float x) {
    return 1.0f - 2.0f / (__expf(2.0f * x) + 1.0f);
}

__device__ __forceinline__ short bf16s(float x) {
    __hip_bfloat16 h = __float2bfloat16(x);
    return *reinterpret_cast<short*>(&h);
}

__device__ __forceinline__ float bf2f(unsigned short u) {
    unsigned v = ((unsigned)u) << 16;
    float f;
    __builtin_memcpy(&f, &v, 4);
    return f;
}

// min of the 4 per-wave flags in one slot (4 independent sc1 loads, pipelined)
__device__ __forceinline__ unsigned min4flags(const unsigned* p) {
    const unsigned a = __hip_atomic_load(p + 0, __ATOMIC_RELAXED, __HIP_MEMORY_SCOPE_AGENT);
    const unsigned b = __hip_atomic_load(p + 1, __ATOMIC_RELAXED, __HIP_MEMORY_SCOPE_AGENT);
    const unsigned c = __hip_atomic_load(p + 2, __ATOMIC_RELAXED, __HIP_MEMORY_SCOPE_AGENT);
    const unsigned d = __hip_atomic_load(p + 3, __ATOMIC_RELAXED, __HIP_MEMORY_SCOPE_AGENT);
    const unsigned ab = a < b ? a : b;
    const unsigned cd = c < d ? c : d;
    return ab < cd ? ab : cd;
}

__device__ __forceinline__ shortx8 cvt8(const float* __restrict__ p) {
    float4 v0 = *(const float4*)p;
    float4 v1 = *(const float4*)(p + 4);
    shortx8 r;
    r[0] = bf16s(v0.x); r[1] = bf16s(v0.y); r[2] = bf16s(v0.z); r[3] = bf16s(v0.w);
    r[4] = bf16s(v1.x); r[5] = bf16s(v1.y); r[6] = bf16s(v1.z); r[7] = bf16s(v1.w);
    return r;
}

// ---------------------------------------------------------------------------
// Fused fp32 -> bf16 conversion of ALL weights in one launch.
// grid = 4*2048 (gates) + 1024 (Wfc) = 9216 blocks x 256.
// ---------------------------------------------------------------------------
__global__ __launch_bounds__(256) void cvt_weights(
    const float* __restrict__ Wf, const float* __restrict__ Wi,
    const float* __restrict__ Wc, const float* __restrict__ Wo,
    const float* __restrict__ Wfc,
    __hip_bfloat16* __restrict__ Wb, __hip_bfloat16* __restrict__ Wfcb)
{
    int b = blockIdx.x;
    const float* src;
    __hip_bfloat16* dst;
    if (b < 8192) {
        const int g = b >> 11;
        src = (g == 0) ? Wf : (g == 1) ? Wi : (g == 2) ? Wc : Wo;
        dst = Wb + (size_t)g * WG_ELEMS;
        b &= 2047;
    } else {
        src = Wfc; dst = Wfcb; b -= 8192;
    }
    const int i = (b * 256 + threadIdx.x) * 4;
    float4 v = *(const float4*)(src + i);
    dst[i + 0] = __float2bfloat16(v.x);
    dst[i + 1] = __float2bfloat16(v.y);
    dst[i + 2] = __float2bfloat16(v.z);
    dst[i + 3] = __float2bfloat16(v.w);
}

// ---------------------------------------------------------------------------
// Kernel 1 (FALLBACK only): x-part gate pre-activations for a chunk of T
// steps. Gx[(t-t0)*B + b][g*1024+j] = sum_k x[b][t][k]*Wg[j][1024+k] + bias.
// grid = T*8 blocks of 256.
// ---------------------------------------------------------------------------
__global__ __launch_bounds__(256) void gemm_gx(
    const float* __restrict__ x,
    const __hip_bfloat16* __restrict__ Wb,     // [4][1024][2048] bf16
    const float* __restrict__ bf_, const float* __restrict__ bi_,
    const float* __restrict__ bc_, const float* __restrict__ bo_,
    __hip_bfloat16* __restrict__ Gx, const int t0)
{
    const int wave = (blockIdx.x << 2) + (threadIdx.x >> 6);
    const int mt = wave >> 6;
    const int nt = wave & 63;
    const int lane = threadIdx.x & 63;
    const int quad = lane >> 4;
    const int l16  = lane & 15;
    const int m0 = mt << 6;
    const int n0 = nt << 6;
    const int g  = n0 >> 10;
    const __hip_bfloat16* Wg = Wb + (size_t)g * WG_ELEMS;
    const float* bg = (g == 0) ? bf_ : (g == 1) ? bi_ : (g == 2) ? bc_ : bo_;
    const int j0 = n0 & 1023;

    floatx4 acc[4][4];
#pragma unroll
    for (int i = 0; i < 4; i++)
#pragma unroll
        for (int j = 0; j < 4; j++) acc[i][j] = (floatx4)(0.0f);

    const float* arow[4];
    const __hip_bfloat16* brow[4];
#pragma unroll
    for (int i = 0; i < 4; i++) {
        const int r = m0 + i * 16 + l16;
        const int t = t0 + (r >> 5);
        const int b = r & 31;
        arow[i] = x + ((size_t)b * SEQ + t) * IND + quad * 8;
    }
#pragma unroll
    for (int j = 0; j < 4; j++)
        brow[j] = Wg + (size_t)(j0 + j * 16 + l16) * ZD + HD + quad * 8;

    for (int k0 = 0; k0 < IND; k0 += 32) {
        shortx8 a[4], b[4];
#pragma unroll
        for (int i = 0; i < 4; i++) a[i] = cvt8(arow[i] + k0);
#pragma unroll
        for (int j = 0; j < 4; j++) b[j] = *(const shortx8*)(brow[j] + k0);
#pragma unroll
        for (int i = 0; i < 4; i++)
#pragma unroll
            for (int j = 0; j < 4; j++)
                acc[i][j] = MFMA16(a[i], b[j], acc[i][j]);
    }

#pragma unroll
    for (int j = 0; j < 4; j++) {
        const int n  = n0 + j * 16 + l16;
        const int jj = j0 + j * 16 + l16;
        const float bias = bg[jj];
#pragma unroll
        for (int i = 0; i < 4; i++) {
#pragma unroll
            for (int r = 0; r < 4; r++) {
                const int row = m0 + i * 16 + quad * 4 + r;
                Gx[(size_t)row * NG + n] = __float2bfloat16(acc[i][j][r] + bias);
            }
        }
    }
}

// ---------------------------------------------------------------------------
// Kernel 2 (FALLBACK, small-ws path): one LSTM time step, hs-direct h I/O.
// ---------------------------------------------------------------------------
__global__ __launch_bounds__(256) void lstm_step(
    const __hip_bfloat16* __restrict__ gx,
    const int t,
    const __hip_bfloat16* __restrict__ Wb,
    const __hip_bfloat16* __restrict__ hzero,  // [B][H] zeros
    float* __restrict__ c,
    __hip_bfloat16* __restrict__ hs)           // [B][S][H]
{
    const int jt = (blockIdx.x << 2) + (threadIdx.x >> 6);
    const int lane = threadIdx.x & 63;
    const int quad = lane >> 4;
    const int l16  = lane & 15;
    const int j0   = jt << 4;

    const __hip_bfloat16* hb;
    size_t rstride;
    if (t == 0) { hb = hzero; rstride = HD; }
    else        { hb = hs + (size_t)(t - 1) * HD; rstride = (size_t)SEQ * HD; }

    const __hip_bfloat16* wrow[4];
#pragma unroll
    for (int g = 0; g < 4; g++)
        wrow[g] = Wb + (size_t)g * WG_ELEMS + (size_t)(j0 + l16) * ZD + quad * 8;

    const __hip_bfloat16* hrow0 = hb + (size_t)l16 * rstride + quad * 8;
    const __hip_bfloat16* hrow1 = hb + (size_t)(16 + l16) * rstride + quad * 8;

    floatx4 acc[4][2];
#pragma unroll
    for (int g = 0; g < 4; g++) { acc[g][0] = (floatx4)(0.0f); acc[g][1] = (floatx4)(0.0f); }

    for (int k0 = 0; k0 < HD; k0 += 32) {
        shortx8 a0 = *(const shortx8*)(hrow0 + k0);
        shortx8 a1 = *(const shortx8*)(hrow1 + k0);
#pragma unroll
        for (int g = 0; g < 4; g++) {
            shortx8 bfrag = *(const shortx8*)(wrow[g] + k0);
            acc[g][0] = MFMA16(a0, bfrag, acc[g][0]);
            acc[g][1] = MFMA16(a1, bfrag, acc[g][1]);
        }
    }

    const int j = j0 + l16;
#pragma unroll
    for (int i = 0; i < 2; i++) {
#pragma unroll
        for (int r = 0; r < 4; r++) {
            const int bb = i * 16 + quad * 4 + r;
            const size_t gbase = (size_t)bb * NG + j;
            const float fp = acc[0][i][r] + __bfloat162float(gx[gbase + 0 * HD]);
            const float ip = acc[1][i][r] + __bfloat162float(gx[gbase + 1 * HD]);
            const float cp = acc[2][i][r] + __bfloat162float(gx[gbase + 2 * HD]);
            const float op = acc[3][i][r] + __bfloat162float(gx[gbase + 3 * HD]);
            const float fg = sigmoidf_(fp);
            const float ig = sigmoidf_(ip);
            const float cg = tanhf_(cp);
            const float og = sigmoidf_(op);
            const size_t ci = (size_t)bb * HD + j;
            const float cnew = ig * cg + fg * c[ci];
            const float hnew = og * tanhf_(cnew);
            c[ci] = cnew;
            hs[((size_t)bb * SEQ + t) * HD + j] = __float2bfloat16(hnew);
        }
    }
}

// ---------------------------------------------------------------------------
// Kernel 2' (FAST path): persistent recurrence + concurrent Gx + fused FC, v13.
//
// v13 = v11 consumer structure (upfront per-wave wait, pipelined loads) with
// barrier (B) DELETED:
//  - PER-WAVE FLAG PUBLISH: each consumer wave drains its OWN h stores
//    (inline s_waitcnt vmcnt(0), the proven producer-side mechanism) and
//    publishes its own flag bar[blk*FSTR + wv] = tt+1. No block rendezvous
//    before publication; fast waves roll into step t+1 immediately.
//  - Consumers wait on min of the 4 per-wave flags per source block (one
//    272B slot, 4 pipelined sc1 loads per poll; divergent-while converges
//    the wave on all 64 source blocks).
//  - accf LDS panels DOUBLE-BUFFERED by step parity (WAR safety without
//    barrier (B): panels[p] is rewritten at step t+2 only after sync(A)@t+1,
//    which happens-after every wave's pointwise@t by program order).
// (v11, kept): FC gate wave0-poll + broadcast (now min-of-4); 272B-stride
// slots; relaxed sc1 data stores; v12's per-fragment gating REVERTED (it
// issue-serialized the A-frag loads: -19%).
// ---------------------------------------------------------------------------
__global__ __launch_bounds__(256, 1) void lstm_persist(
    const __hip_bfloat16* __restrict__ Wb,     // [4][1024][2048] bf16
    const float* __restrict__ x,               // [B][S][IND] fp32
    __hip_bfloat16* __restrict__ Gx,           // [S*B][NG] bf16 (full)
    const float* __restrict__ bf_, const float* __restrict__ bi_,
    const float* __restrict__ bc_, const float* __restrict__ bo_,
    const __hip_bfloat16* __restrict__ Wfcb,   // [1024][1024] bf16
    const float* __restrict__ bfc,
    float* __restrict__ out,                   // [B*S][1024] fp32
    const int T,
    const __hip_bfloat16* __restrict__ hzero,  // [B][H] zeros
    float* __restrict__ c_ws,                  // [PBLK*256] fp32
    __hip_bfloat16* __restrict__ hs,           // [B][S][H] bf16
    unsigned* __restrict__ bar)  // arrive[128]*FSTR (4 u32/slot); +128*FSTR: gcnt
{
    __shared__ float accf[2][2 * 1168];        // double-buffered by step parity

    const int tid  = threadIdx.x;
    const int blk  = blockIdx.x;
    const int wv   = tid >> 6;
    const int lane = tid & 63;
    const int quad = lane >> 4;
    const int l16  = lane & 15;
    unsigned* gcnt = bar + 128 * FSTR;

    if (blk >= PBLK) {
        // ========================= PRODUCER =========================
        const int pb_ = blk - PBLK;              // 0..127
        const int pw = pb_ * 4 + wv;             // 0..511
        {
            const int nt = pw & 63;              // fixed col-tile (W stays L2-hot)
            const int n0 = nt << 6;
            const int g  = n0 >> 10;
            const __hip_bfloat16* Wg = Wb + (size_t)g * WG_ELEMS;
            const float* bg = (g == 0) ? bf_ : (g == 1) ? bi_ : (g == 2) ? bc_ : bo_;
            const int j0 = n0 & 1023;

            const __hip_bfloat16* brow[4];
#pragma unroll
            for (int j = 0; j < 4; j++)
                brow[j] = Wg + (size_t)(j0 + j * 16 + l16) * ZD + HD + quad * 8;

            float bias[4];
#pragma unroll
            for (int j = 0; j < 4; j++) bias[j] = bg[j0 + j * 16 + l16];

            for (int it = 0; it < 32; it++) {
                const int mt = (pw >> 6) + 8 * it;  // rows [mt*64, +64) = t-pair
                const int m0 = mt << 6;

                floatx4 acc[4][4];
#pragma unroll
                for (int i = 0; i < 4; i++)
#pragma unroll
                    for (int j = 0; j < 4; j++) acc[i][j] = (floatx4)(0.0f);

                const float* arow[4];
#pragma unroll
                for (int i = 0; i < 4; i++) {
                    const int r = m0 + i * 16 + l16;
                    const int t = r >> 5;
                    const int b = r & 31;
                    arow[i] = x + ((size_t)b * SEQ + t) * IND + quad * 8;
                }

                for (int k0 = 0; k0 < IND; k0 += 32) {
                    shortx8 a[4], b[4];
#pragma unroll
                    for (int i = 0; i < 4; i++) a[i] = cvt8(arow[i] + k0);
#pragma unroll
                    for (int j = 0; j < 4; j++) b[j] = *(const shortx8*)(brow[j] + k0);
#pragma unroll
                    for (int i = 0; i < 4; i++)
#pragma unroll
                        for (int j = 0; j < 4; j++)
                            acc[i][j] = MFMA16(a[i], b[j], acc[i][j]);
                }

                // packed-u32 relaxed sc1 stores (coherence-point visible)
#pragma unroll
                for (int j = 0; j < 4; j++) {
                    const int n = n0 + j * 16 + l16;
#pragma unroll
                    for (int i = 0; i < 4; i++) {
#pragma unroll
                        for (int r = 0; r < 4; r++) {
                            const int row = m0 + i * 16 + quad * 4 + r;
                            const float v = acc[i][j][r] + bias[j];
                            const unsigned my = (unsigned)(unsigned short)bf16s(v);
                            const unsigned nb = (unsigned)__shfl_xor((int)my, 1);
                            if ((l16 & 1) == 0) {
                                unsigned* dst = (unsigned*)(Gx + (size_t)row * NG + n);
                                __hip_atomic_store(dst, my | (nb << 16),
                                                   __ATOMIC_RELAXED,
                                                   __HIP_MEMORY_SCOPE_AGENT);
                            }
                        }
                    }
                }
                // drain sc1 data stores to the coherence point, then signal
                asm volatile("s_waitcnt vmcnt(0)" ::: "memory");
                if (lane == 0)
                    __hip_atomic_fetch_add(gcnt + (size_t)mt * FSTR, 1u,
                                           __ATOMIC_RELAXED, __HIP_MEMORY_SCOPE_AGENT);
            }
        }

        // ---------------- FC phase: out = hs @ Wfc^T + bfc ----------------
        {
            const int fb  = (pb_ & 7) * 4 + wv;  // batch 0..31 (same-XCD group)
            const int fnt = pb_ >> 3;            // col-tile 0..15
            const int n0  = fnt << 6;

            const __hip_bfloat16* brow[4];
#pragma unroll
            for (int j = 0; j < 4; j++)
                brow[j] = Wfcb + (size_t)(n0 + j * 16 + l16) * HD + quad * 8;
            float biasf[4];
#pragma unroll
            for (int j = 0; j < 4; j++) biasf[j] = bfc[n0 + j * 16 + l16];

            for (int tc = 0; tc < 8; tc++) {
                // gate: all consumer waves' epochs >= (tc+1)*64 — wave0 polls
                // the min-of-4 per slot, then __syncthreads broadcasts
                const unsigned need = (unsigned)((tc + 1) * 64);
                if (wv == 0) {
                    const unsigned* p0 = bar + (size_t)lane * FSTR;
                    const unsigned* p1 = bar + (size_t)(64 + lane) * FSTR;
                    bool d0 = false, d1 = false;
                    while (true) {
                        if (!d0) d0 = (min4flags(p0) >= need);
                        if (!d1) d1 = (min4flags(p1) >= need);
                        if (__all(d0 && d1)) break;
                        __builtin_amdgcn_s_sleep(8);
                    }
                    asm volatile("" ::: "memory");
                    __builtin_amdgcn_sched_barrier(0);
                }
                __syncthreads();

                const int m0 = fb * SEQ + tc * 64;

                floatx4 acc[4][4];
#pragma unroll
                for (int i = 0; i < 4; i++)
#pragma unroll
                    for (int j = 0; j < 4; j++) acc[i][j] = (floatx4)(0.0f);

                const __hip_bfloat16* arow[4];
#pragma unroll
                for (int i = 0; i < 4; i++)
                    arow[i] = hs + (size_t)(m0 + i * 16 + l16) * HD + quad * 8;

                for (int k0 = 0; k0 < HD; k0 += 32) {
                    shortx8 a[4], b[4];
#pragma unroll
                    for (int i = 0; i < 4; i++) a[i] = *(const shortx8*)(arow[i] + k0);
#pragma unroll
                    for (int j = 0; j < 4; j++) b[j] = *(const shortx8*)(brow[j] + k0);
#pragma unroll
                    for (int i = 0; i < 4; i++)
#pragma unroll
                        for (int j = 0; j < 4; j++)
                            acc[i][j] = MFMA16(a[i], b[j], acc[i][j]);
                }

#pragma unroll
                for (int j = 0; j < 4; j++) {
                    const int n = n0 + j * 16 + l16;
#pragma unroll
                    for (int i = 0; i < 4; i++) {
#pragma unroll
                        for (int r = 0; r < 4; r++) {
                            const int row = m0 + i * 16 + quad * 4 + r;
                            out[(size_t)row * 1024 + n] = acc[i][j][r] + biasf[j];
                        }
                    }
                }
            }
        }
        return;
    }

    // ========================= CONSUMER =========================
    const int wm = wv & 1;           // batch-half tile
    const int wk = wv >> 1;          // K-half

    shortx8 Bfrag[2][16];
#pragma unroll
    for (int ct = 0; ct < 2; ct++) {
        const int lc = ct * 16 + l16;
        const int jj = lc >> 2, g = lc & 3;
        const __hip_bfloat16* wr =
            Wb + (size_t)g * WG_ELEMS + (size_t)(blk * 8 + jj) * ZD + wk * 512 + quad * 8;
#pragma unroll
        for (int ks = 0; ks < 16; ks++)
            Bfrag[ct][ks] = *(const shortx8*)(wr + ks * 32);
    }

    const int pjj = tid & 7;
    const int pb  = tid >> 3;
    const int pj  = blk * 8 + pjj;
    float creg = c_ws[blk * 256 + tid];

    // prologue: wait for Gx rows of t=0 (mt 0) — wave0 polls, sync broadcasts
    if (wv == 0) {
        while (__hip_atomic_load(gcnt, __ATOMIC_RELAXED,
                                 __HIP_MEMORY_SCOPE_AGENT) < 64)
            __builtin_amdgcn_s_sleep(1);
        asm volatile("" ::: "memory");
        __builtin_amdgcn_sched_barrier(0);
    }
    __syncthreads();

    unsigned short gxr0, gxr1, gxr2, gxr3;
    {
        const __hip_bfloat16* gx = Gx + (size_t)pb * NG + pj;
        gxr0 = *(const unsigned short*)(gx + 0 * HD);
        gxr1 = *(const unsigned short*)(gx + 1 * HD);
        gxr2 = *(const unsigned short*)(gx + 2 * HD);
        gxr3 = *(const unsigned short*)(gx + 3 * HD);
    }
    int mt_ok = 0;

    // lane L watches source block wk*64+L (min over its 4 per-wave flags)
    const unsigned* mywatch = bar + (size_t)(wk * 64 + lane) * FSTR;

    for (int tt = 0; tt < T; tt++) {
        const int t = tt;
        const __hip_bfloat16* hb;
        size_t rstride;
        if (t == 0) { hb = hzero; rstride = HD; }
        else        { hb = hs + (size_t)(t - 1) * HD; rstride = (size_t)SEQ * HD; }

        // gx prefetch for tt+1 (gcnt-gated; issues before the flag wait so
        // the loads complete under the spin)
        unsigned short ngxr0 = 0, ngxr1 = 0, ngxr2 = 0, ngxr3 = 0;
        if (tt + 1 < T) {
            const int mtn = (tt + 1) >> 1;
            if (mtn > mt_ok) {
                while (__hip_atomic_load(gcnt + (size_t)mtn * FSTR, __ATOMIC_RELAXED,
                                         __HIP_MEMORY_SCOPE_AGENT) < 64)
                    __builtin_amdgcn_s_sleep(1);
                mt_ok = mtn;
                asm volatile("" ::: "memory");
                __builtin_amdgcn_sched_barrier(0);
            }
            const __hip_bfloat16* gx1 = Gx + ((size_t)(tt + 1) * BATCH + pb) * NG + pj;
            ngxr0 = *(const unsigned short*)(gx1 + 0 * HD);
            ngxr1 = *(const unsigned short*)(gx1 + 1 * HD);
            ngxr2 = *(const unsigned short*)(gx1 + 2 * HD);
            ngxr3 = *(const unsigned short*)(gx1 + 3 * HD);
        }

        // per-wave half-barrier: wait for this wave's 64 source blocks (all
        // 4 waves each) to have published epoch >= tt (h[tt-1] at IF).
        // Divergent-while; the wave converges when ALL lanes pass.
        if (tt > 0) {
            while (min4flags(mywatch) < (unsigned)tt)
                __builtin_amdgcn_s_sleep(1);
            asm volatile("" ::: "memory");
            __builtin_amdgcn_sched_barrier(0);
        }

        // h @ Wh^T : one A-frag stream feeds BOTH col-tile chains (pipelined)
        const __hip_bfloat16* arow =
            hb + (size_t)(wm * 16 + l16) * rstride + wk * 512 + quad * 8;
        floatx4 acc0 = (floatx4)(0.0f), acc1 = (floatx4)(0.0f);
#pragma unroll
        for (int ks = 0; ks < 16; ks++) {
            shortx8 av = *(const shortx8*)(arow + ks * 32);
            acc0 = MFMA16(av, Bfrag[0][ks], acc0);
            acc1 = MFMA16(av, Bfrag[1][ks], acc1);
        }

        // acc -> LDS panel[tt&1] [wk][col][b], stride 36 floats (16B-aligned)
        float* panel = accf[tt & 1];
        {
            const int b0 = wm * 16 + quad * 4;
            *(floatx4*)(panel + wk * 1168 + (l16)      * 36 + b0) = acc0;
            *(floatx4*)(panel + wk * 1168 + (16 + l16) * 36 + b0) = acc1;
        }
        __syncthreads();   // (A) panels complete

        // pointwise for (pb, pjj); c lives in a register across the launch
        {
            const int i0 = (pjj * 4 + 0) * 36 + pb;
            const int i1 = (pjj * 4 + 1) * 36 + pb;
            const int i2 = (pjj * 4 + 2) * 36 + pb;
            const int i3 = (pjj * 4 + 3) * 36 + pb;
            const float fp = panel[i0] + panel[1168 + i0] + bf2f(gxr0);
            const float ip = panel[i1] + panel[1168 + i1] + bf2f(gxr1);
            const float cp = panel[i2] + panel[1168 + i2] + bf2f(gxr2);
            const float op = panel[i3] + panel[1168 + i3] + bf2f(gxr3);
            const float fg = sigmoidf_(fp);
            const float ig = sigmoidf_(ip);
            const float cg = tanhf_(cp);
            const float og = sigmoidf_(op);
            creg = ig * cg + fg * creg;
            const float hnew = og * tanhf_(creg);

            // packed-u32 relaxed agent store (sc1 => coherence-point visible)
            const unsigned my = (unsigned)(unsigned short)bf16s(hnew);
            const unsigned nb = (unsigned)__shfl_xor((int)my, 1);
            if ((tid & 1) == 0) {
                unsigned* dst = (unsigned*)(hs + ((size_t)pb * SEQ + t) * HD + pj);
                const unsigned packed = my | (nb << 16);
                __hip_atomic_store(dst, packed, __ATOMIC_RELAXED,
                                   __HIP_MEMORY_SCOPE_AGENT);
            }
        }

        // v13: NO barrier (B). Each wave drains its OWN sc1 h stores and
        // publishes its own per-wave flag. Consumers take min over the 4.
        asm volatile("s_waitcnt vmcnt(0)" ::: "memory");
        if (lane == 0) {
            __hip_atomic_store(bar + (size_t)blk * FSTR + wv, (unsigned)(tt + 1),
                               __ATOMIC_RELAXED, __HIP_MEMORY_SCOPE_AGENT);
        }

        gxr0 = ngxr0; gxr1 = ngxr1; gxr2 = ngxr2; gxr3 = ngxr3;
    }

    c_ws[blk * 256 + tid] = creg;
}

// ---------------------------------------------------------------------------
// Kernel 3 (FALLBACK only): out[r][n] = sum_k hs[r][k]*Wfc[n][k] + bfc[n]
// ---------------------------------------------------------------------------
__global__ __launch_bounds__(256) void gemm_fc(
    const __hip_bfloat16* __restrict__ hs,
    const __hip_bfloat16* __restrict__ Wfcb,
    const float* __restrict__ bfc,
    float* __restrict__ out)
{
    const int wave = (blockIdx.x << 2) + (threadIdx.x >> 6);
    const int mt = wave >> 4;
    const int nt = wave & 15;
    const int lane = threadIdx.x & 63;
    const int quad = lane >> 4;
    const int l16  = lane & 15;
    const int m0 = mt << 6;
    const int n0 = nt << 6;

    floatx4 acc[4][4];
#pragma unroll
    for (int i = 0; i < 4; i++)
#pragma unroll
        for (int j = 0; j < 4; j++) acc[i][j] = (floatx4)(0.0f);

    const __hip_bfloat16* arow[4];
    const __hip_bfloat16* brow[4];
#pragma unroll
    for (int i = 0; i < 4; i++)
        arow[i] = hs + (size_t)(m0 + i * 16 + l16) * HD + quad * 8;
#pragma unroll
    for (int j = 0; j < 4; j++)
        brow[j] = Wfcb + (size_t)(n0 + j * 16 + l16) * HD + quad * 8;

    for (int k0 = 0; k0 < HD; k0 += 32) {
        shortx8 a[4], b[4];
#pragma unroll
        for (int i = 0; i < 4; i++) a[i] = *(const shortx8*)(arow[i] + k0);
#pragma unroll
        for (int j = 0; j < 4; j++) b[j] = *(const shortx8*)(brow[j] + k0);
#pragma unroll
        for (int i = 0; i < 4; i++)
#pragma unroll
            for (int j = 0; j < 4; j++)
                acc[i][j] = MFMA16(a[i], b[j], acc[i][j]);
    }

#pragma unroll
    for (int j = 0; j < 4; j++) {
        const int n = n0 + j * 16 + l16;
        const float bias = bfc[n];
#pragma unroll
        for (int i = 0; i < 4; i++) {
#pragma unroll
            for (int r = 0; r < 4; r++) {
                const int row = m0 + i * 16 + quad * 4 + r;
                out[(size_t)row * 1024 + n] = acc[i][j][r] + bias;
            }
        }
    }
}

// ---------------------------------------------------------------------------
extern "C" void kernel_launch(void* const* d_in, const int* in_sizes, int n_in,
                              void* d_out, int out_size, void* d_ws, size_t ws_size,
                              hipStream_t stream) {
    const float* x   = (const float*)d_in[0];
    const float* Wf  = (const float*)d_in[1];
    const float* bf_ = (const float*)d_in[2];
    const float* Wi  = (const float*)d_in[3];
    const float* bi_ = (const float*)d_in[4];
    const float* Wc  = (const float*)d_in[5];
    const float* bc_ = (const float*)d_in[6];
    const float* Wo  = (const float*)d_in[7];
    const float* bo_ = (const float*)d_in[8];
    const float* Wfc = (const float*)d_in[9];
    const float* bfc = (const float*)d_in[10];
    float* out = (float*)d_out;

    // ---- ws layout (bytes) ----
    char* ws = (char*)d_ws;
    const size_t WB_OFF  = 0;                                          // 16 MiB
    const size_t WFC_OFF = (size_t)4 * WG_ELEMS * 2;                   // +2 MiB
    const size_t HS_OFF  = WFC_OFF + (size_t)HD * HD * 2;              // +32 MiB
    const size_t ST_OFF  = HS_OFF + (size_t)BATCH * SEQ * HD * 2;
    const size_t HZ_BYTES  = (size_t)BATCH * HD * 2;                   // 64 KiB
    const size_t C_BYTES   = (size_t)PBLK * 256 * 4;                   // 128 KiB
    const size_t BAR_BYTES = (size_t)(128 + 256) * FSTR * 4;           // ~102 KiB
    const size_t ST_BYTES  = HZ_BYTES + C_BYTES + BAR_BYTES;
    const size_t GX_OFF  = ST_OFF + ST_BYTES;

    __hip_bfloat16* Wb    = (__hip_bfloat16*)(ws + WB_OFF);
    __hip_bfloat16* Wfcb  = (__hip_bfloat16*)(ws + WFC_OFF);
    __hip_bfloat16* hs    = (__hip_bfloat16*)(ws + HS_OFF);
    __hip_bfloat16* hzero = (__hip_bfloat16*)(ws + ST_OFF);
    float*          cbuf  = (float*)(ws + ST_OFF + HZ_BYTES);
    unsigned*       bar   = (unsigned*)(ws + ST_OFF + HZ_BYTES + C_BYTES);
    __hip_bfloat16* Gx    = (__hip_bfloat16*)(ws + GX_OFF);

    // fast path needs the full Gx array (128 MiB)
    const size_t GX_FULL = (size_t)SEQ * BATCH * NG * 2;
    const int persist = (GX_OFF + GX_FULL <= ws_size);
    int T_CHUNK = 1;
    if (!persist) {
        const size_t GX_STEP = (size_t)BATCH * NG * 2;   // 256 KiB per step
        const int fopts[3] = {8, 2, 1};
        for (int i = 0; i < 3; i++) {
            if (GX_OFF + (size_t)fopts[i] * GX_STEP <= ws_size) {
                T_CHUNK = fopts[i]; break;
            }
        }
    }

    // one-time weight conversion fp32 -> bf16 (single fused launch)
    cvt_weights<<<9216, 256, 0, stream>>>(Wf, Wi, Wc, Wo, Wfc, Wb, Wfcb);

    // zero hzero, c, barrier + ready-counter state (ws poisoned every launch)
    hipMemsetAsync(ws + ST_OFF, 0, ST_BYTES, stream);

    if (persist) {
        // single launch: 128 consumer + 128 producer/FC blocks (256 CUs)
        lstm_persist<<<2 * PBLK, 256, 0, stream>>>(
            Wb, x, Gx, bf_, bi_, bc_, bo_, Wfcb, bfc, out,
            SEQ, hzero, cbuf, hs, bar);
    } else {
        for (int t0 = 0; t0 < SEQ; t0 += T_CHUNK) {
            gemm_gx<<<T_CHUNK * 8, 256, 0, stream>>>(
                x, Wb, bf_, bi_, bc_, bo_, Gx, t0);
            for (int t = t0; t < t0 + T_CHUNK; t++) {
                const __hip_bfloat16* gx_t = Gx + (size_t)(t - t0) * BATCH * NG;
                lstm_step<<<16, 256, 0, stream>>>(gx_t, t, Wb, hzero, cbuf, hs);
            }
        }
        gemm_fc<<<1024, 256, 0, stream>>>(hs, Wfcb, bfc, out);
    }
}

// Round 12
// 2391.144 us; speedup vs baseline: 1.5085x; 1.5085x over previous
//
#include <hip/hip_runtime.h>
#include <hip/hip_bf16.h>

#define BATCH 32
#define SEQ   512
#define IND   1024
#define HD    1024
#define ZD    2048   // IN + H
#define NG    4096   // 4*H
#define WG_ELEMS (1024 * 2048)   // elements per gate weight matrix
#define PBLK 128                 // consumer grid size (producers: PBLK..2*PBLK)
#define FSTR 68                  // flag slot stride in u32 (272B: stripes channels)

typedef short  shortx8 __attribute__((ext_vector_type(8)));
typedef float  floatx4 __attribute__((ext_vector_type(4)));

#define MFMA16(a, b, c) __builtin_amdgcn_mfma_f32_16x16x32_bf16((a), (b), (c), 0, 0, 0)

__device__ __forceinline__ float sigmoidf_(float x) {
    return 1.0f / (1.0f + __expf(-x));
}
__device__ __forceinline__ float tanhf_(float x) {
    return 1.0f - 2.0f / (__expf(2.0f * x) + 1.0f);
}

__device__ __forceinline__ short bf16s(float x) {
    __hip_bfloat16 h = __float2bfloat16(x);
    return *reinterpret_cast<short*>(&h);
}

__device__ __forceinline__ float bf2f(unsigned short u) {
    unsigned v = ((unsigned)u) << 16;
    float f;
    __builtin_memcpy(&f, &v, 4);
    return f;
}

__device__ __forceinline__ shortx8 cvt8(const float* __restrict__ p) {
    float4 v0 = *(const float4*)p;
    float4 v1 = *(const float4*)(p + 4);
    shortx8 r;
    r[0] = bf16s(v0.x); r[1] = bf16s(v0.y); r[2] = bf16s(v0.z); r[3] = bf16s(v0.w);
    r[4] = bf16s(v1.x); r[5] = bf16s(v1.y); r[6] = bf16s(v1.z); r[7] = bf16s(v1.w);
    return r;
}

// ---------------------------------------------------------------------------
// Fused fp32 -> bf16 conversion of ALL weights in one launch.
// grid = 4*2048 (gates) + 1024 (Wfc) = 9216 blocks x 256.
// ---------------------------------------------------------------------------
__global__ __launch_bounds__(256) void cvt_weights(
    const float* __restrict__ Wf, const float* __restrict__ Wi,
    const float* __restrict__ Wc, const float* __restrict__ Wo,
    const float* __restrict__ Wfc,
    __hip_bfloat16* __restrict__ Wb, __hip_bfloat16* __restrict__ Wfcb)
{
    int b = blockIdx.x;
    const float* src;
    __hip_bfloat16* dst;
    if (b < 8192) {
        const int g = b >> 11;
        src = (g == 0) ? Wf : (g == 1) ? Wi : (g == 2) ? Wc : Wo;
        dst = Wb + (size_t)g * WG_ELEMS;
        b &= 2047;
    } else {
        src = Wfc; dst = Wfcb; b -= 8192;
    }
    const int i = (b * 256 + threadIdx.x) * 4;
    float4 v = *(const float4*)(src + i);
    dst[i + 0] = __float2bfloat16(v.x);
    dst[i + 1] = __float2bfloat16(v.y);
    dst[i + 2] = __float2bfloat16(v.z);
    dst[i + 3] = __float2bfloat16(v.w);
}

// ---------------------------------------------------------------------------
// Kernel 1 (FALLBACK only): x-part gate pre-activations for a chunk of T
// steps. Gx[(t-t0)*B + b][g*1024+j] = sum_k x[b][t][k]*Wg[j][1024+k] + bias.
// grid = T*8 blocks of 256.
// ---------------------------------------------------------------------------
__global__ __launch_bounds__(256) void gemm_gx(
    const float* __restrict__ x,
    const __hip_bfloat16* __restrict__ Wb,     // [4][1024][2048] bf16
    const float* __restrict__ bf_, const float* __restrict__ bi_,
    const float* __restrict__ bc_, const float* __restrict__ bo_,
    __hip_bfloat16* __restrict__ Gx, const int t0)
{
    const int wave = (blockIdx.x << 2) + (threadIdx.x >> 6);
    const int mt = wave >> 6;
    const int nt = wave & 63;
    const int lane = threadIdx.x & 63;
    const int quad = lane >> 4;
    const int l16  = lane & 15;
    const int m0 = mt << 6;
    const int n0 = nt << 6;
    const int g  = n0 >> 10;
    const __hip_bfloat16* Wg = Wb + (size_t)g * WG_ELEMS;
    const float* bg = (g == 0) ? bf_ : (g == 1) ? bi_ : (g == 2) ? bc_ : bo_;
    const int j0 = n0 & 1023;

    floatx4 acc[4][4];
#pragma unroll
    for (int i = 0; i < 4; i++)
#pragma unroll
        for (int j = 0; j < 4; j++) acc[i][j] = (floatx4)(0.0f);

    const float* arow[4];
    const __hip_bfloat16* brow[4];
#pragma unroll
    for (int i = 0; i < 4; i++) {
        const int r = m0 + i * 16 + l16;
        const int t = t0 + (r >> 5);
        const int b = r & 31;
        arow[i] = x + ((size_t)b * SEQ + t) * IND + quad * 8;
    }
#pragma unroll
    for (int j = 0; j < 4; j++)
        brow[j] = Wg + (size_t)(j0 + j * 16 + l16) * ZD + HD + quad * 8;

    for (int k0 = 0; k0 < IND; k0 += 32) {
        shortx8 a[4], b[4];
#pragma unroll
        for (int i = 0; i < 4; i++) a[i] = cvt8(arow[i] + k0);
#pragma unroll
        for (int j = 0; j < 4; j++) b[j] = *(const shortx8*)(brow[j] + k0);
#pragma unroll
        for (int i = 0; i < 4; i++)
#pragma unroll
            for (int j = 0; j < 4; j++)
                acc[i][j] = MFMA16(a[i], b[j], acc[i][j]);
    }

#pragma unroll
    for (int j = 0; j < 4; j++) {
        const int n  = n0 + j * 16 + l16;
        const int jj = j0 + j * 16 + l16;
        const float bias = bg[jj];
#pragma unroll
        for (int i = 0; i < 4; i++) {
#pragma unroll
            for (int r = 0; r < 4; r++) {
                const int row = m0 + i * 16 + quad * 4 + r;
                Gx[(size_t)row * NG + n] = __float2bfloat16(acc[i][j][r] + bias);
            }
        }
    }
}

// ---------------------------------------------------------------------------
// Kernel 2 (FALLBACK, small-ws path): one LSTM time step, hs-direct h I/O.
// ---------------------------------------------------------------------------
__global__ __launch_bounds__(256) void lstm_step(
    const __hip_bfloat16* __restrict__ gx,
    const int t,
    const __hip_bfloat16* __restrict__ Wb,
    const __hip_bfloat16* __restrict__ hzero,  // [B][H] zeros
    float* __restrict__ c,
    __hip_bfloat16* __restrict__ hs)           // [B][S][H]
{
    const int jt = (blockIdx.x << 2) + (threadIdx.x >> 6);
    const int lane = threadIdx.x & 63;
    const int quad = lane >> 4;
    const int l16  = lane & 15;
    const int j0   = jt << 4;

    const __hip_bfloat16* hb;
    size_t rstride;
    if (t == 0) { hb = hzero; rstride = HD; }
    else        { hb = hs + (size_t)(t - 1) * HD; rstride = (size_t)SEQ * HD; }

    const __hip_bfloat16* wrow[4];
#pragma unroll
    for (int g = 0; g < 4; g++)
        wrow[g] = Wb + (size_t)g * WG_ELEMS + (size_t)(j0 + l16) * ZD + quad * 8;

    const __hip_bfloat16* hrow0 = hb + (size_t)l16 * rstride + quad * 8;
    const __hip_bfloat16* hrow1 = hb + (size_t)(16 + l16) * rstride + quad * 8;

    floatx4 acc[4][2];
#pragma unroll
    for (int g = 0; g < 4; g++) { acc[g][0] = (floatx4)(0.0f); acc[g][1] = (floatx4)(0.0f); }

    for (int k0 = 0; k0 < HD; k0 += 32) {
        shortx8 a0 = *(const shortx8*)(hrow0 + k0);
        shortx8 a1 = *(const shortx8*)(hrow1 + k0);
#pragma unroll
        for (int g = 0; g < 4; g++) {
            shortx8 bfrag = *(const shortx8*)(wrow[g] + k0);
            acc[g][0] = MFMA16(a0, bfrag, acc[g][0]);
            acc[g][1] = MFMA16(a1, bfrag, acc[g][1]);
        }
    }

    const int j = j0 + l16;
#pragma unroll
    for (int i = 0; i < 2; i++) {
#pragma unroll
        for (int r = 0; r < 4; r++) {
            const int bb = i * 16 + quad * 4 + r;
            const size_t gbase = (size_t)bb * NG + j;
            const float fp = acc[0][i][r] + __bfloat162float(gx[gbase + 0 * HD]);
            const float ip = acc[1][i][r] + __bfloat162float(gx[gbase + 1 * HD]);
            const float cp = acc[2][i][r] + __bfloat162float(gx[gbase + 2 * HD]);
            const float op = acc[3][i][r] + __bfloat162float(gx[gbase + 3 * HD]);
            const float fg = sigmoidf_(fp);
            const float ig = sigmoidf_(ip);
            const float cg = tanhf_(cp);
            const float og = sigmoidf_(op);
            const size_t ci = (size_t)bb * HD + j;
            const float cnew = ig * cg + fg * c[ci];
            const float hnew = og * tanhf_(cnew);
            c[ci] = cnew;
            hs[((size_t)bb * SEQ + t) * HD + j] = __float2bfloat16(hnew);
        }
    }
}

// ---------------------------------------------------------------------------
// Kernel 2' (FAST path): persistent recurrence + concurrent Gx + fused FC, v11
// (REVERTED to the best-measured configuration; v12 per-fragment gating and
// v13 per-wave flags both regressed — v12 issue-serialized the A-frag loads,
// v13 quadrupled publish+poll traffic on the flag fabric).
//
// Structure:
//  - blocks 0..127 (CONSUMERS): wave (wm=batch-half, wk=K-half) computes both
//    16-col tiles of h@Wh^T over K=512 from global hs[t-1]; 2-panel LDS
//    reduce; pointwise; gx prefetched 1 step ahead; per-wave half-barrier
//    (wave wk polls only its 64 source-block flags, one per lane, divergent
//    sticky spin); publish after the drain barrier, every step.
//  - blocks 128..255 (PRODUCERS): full Gx array (64x64 tiles, bias folded,
//    packed-u32 relaxed sc1 stores, vmcnt drain, gcnt[mt]+1), then the FC
//    GEMM epoch-gated on consumer progress (wave0 polls, barrier broadcast).
//  - 272B-stride flag slots (stripe channels); relaxed sc1 data stores
//    everywhere (coherence-point visible without agent-release wbl2).
// ---------------------------------------------------------------------------
__global__ __launch_bounds__(256, 1) void lstm_persist(
    const __hip_bfloat16* __restrict__ Wb,     // [4][1024][2048] bf16
    const float* __restrict__ x,               // [B][S][IND] fp32
    __hip_bfloat16* __restrict__ Gx,           // [S*B][NG] bf16 (full)
    const float* __restrict__ bf_, const float* __restrict__ bi_,
    const float* __restrict__ bc_, const float* __restrict__ bo_,
    const __hip_bfloat16* __restrict__ Wfcb,   // [1024][1024] bf16
    const float* __restrict__ bfc,
    float* __restrict__ out,                   // [B*S][1024] fp32
    const int T,
    const __hip_bfloat16* __restrict__ hzero,  // [B][H] zeros
    float* __restrict__ c_ws,                  // [PBLK*256] fp32
    __hip_bfloat16* __restrict__ hs,           // [B][S][H] bf16
    unsigned* __restrict__ bar)  // arrive[128]*FSTR; +128*FSTR: gcnt[256]*FSTR
{
    __shared__ float accf[2 * 1168];

    const int tid  = threadIdx.x;
    const int blk  = blockIdx.x;
    const int wv   = tid >> 6;
    const int lane = tid & 63;
    const int quad = lane >> 4;
    const int l16  = lane & 15;
    unsigned* gcnt = bar + 128 * FSTR;

    if (blk >= PBLK) {
        // ========================= PRODUCER =========================
        const int pb_ = blk - PBLK;              // 0..127
        const int pw = pb_ * 4 + wv;             // 0..511
        {
            const int nt = pw & 63;              // fixed col-tile (W stays L2-hot)
            const int n0 = nt << 6;
            const int g  = n0 >> 10;
            const __hip_bfloat16* Wg = Wb + (size_t)g * WG_ELEMS;
            const float* bg = (g == 0) ? bf_ : (g == 1) ? bi_ : (g == 2) ? bc_ : bo_;
            const int j0 = n0 & 1023;

            const __hip_bfloat16* brow[4];
#pragma unroll
            for (int j = 0; j < 4; j++)
                brow[j] = Wg + (size_t)(j0 + j * 16 + l16) * ZD + HD + quad * 8;

            float bias[4];
#pragma unroll
            for (int j = 0; j < 4; j++) bias[j] = bg[j0 + j * 16 + l16];

            for (int it = 0; it < 32; it++) {
                const int mt = (pw >> 6) + 8 * it;  // rows [mt*64, +64) = t-pair
                const int m0 = mt << 6;

                floatx4 acc[4][4];
#pragma unroll
                for (int i = 0; i < 4; i++)
#pragma unroll
                    for (int j = 0; j < 4; j++) acc[i][j] = (floatx4)(0.0f);

                const float* arow[4];
#pragma unroll
                for (int i = 0; i < 4; i++) {
                    const int r = m0 + i * 16 + l16;
                    const int t = r >> 5;
                    const int b = r & 31;
                    arow[i] = x + ((size_t)b * SEQ + t) * IND + quad * 8;
                }

                for (int k0 = 0; k0 < IND; k0 += 32) {
                    shortx8 a[4], b[4];
#pragma unroll
                    for (int i = 0; i < 4; i++) a[i] = cvt8(arow[i] + k0);
#pragma unroll
                    for (int j = 0; j < 4; j++) b[j] = *(const shortx8*)(brow[j] + k0);
#pragma unroll
                    for (int i = 0; i < 4; i++)
#pragma unroll
                        for (int j = 0; j < 4; j++)
                            acc[i][j] = MFMA16(a[i], b[j], acc[i][j]);
                }

                // packed-u32 relaxed sc1 stores (coherence-point visible)
#pragma unroll
                for (int j = 0; j < 4; j++) {
                    const int n = n0 + j * 16 + l16;
#pragma unroll
                    for (int i = 0; i < 4; i++) {
#pragma unroll
                        for (int r = 0; r < 4; r++) {
                            const int row = m0 + i * 16 + quad * 4 + r;
                            const float v = acc[i][j][r] + bias[j];
                            const unsigned my = (unsigned)(unsigned short)bf16s(v);
                            const unsigned nb = (unsigned)__shfl_xor((int)my, 1);
                            if ((l16 & 1) == 0) {
                                unsigned* dst = (unsigned*)(Gx + (size_t)row * NG + n);
                                __hip_atomic_store(dst, my | (nb << 16),
                                                   __ATOMIC_RELAXED,
                                                   __HIP_MEMORY_SCOPE_AGENT);
                            }
                        }
                    }
                }
                // drain sc1 data stores to the coherence point, then signal
                asm volatile("s_waitcnt vmcnt(0)" ::: "memory");
                if (lane == 0)
                    __hip_atomic_fetch_add(gcnt + (size_t)mt * FSTR, 1u,
                                           __ATOMIC_RELAXED, __HIP_MEMORY_SCOPE_AGENT);
            }
        }

        // ---------------- FC phase: out = hs @ Wfc^T + bfc ----------------
        {
            const int fb  = (pb_ & 7) * 4 + wv;  // batch 0..31 (same-XCD group)
            const int fnt = pb_ >> 3;            // col-tile 0..15
            const int n0  = fnt << 6;

            const __hip_bfloat16* brow[4];
#pragma unroll
            for (int j = 0; j < 4; j++)
                brow[j] = Wfcb + (size_t)(n0 + j * 16 + l16) * HD + quad * 8;
            float biasf[4];
#pragma unroll
            for (int j = 0; j < 4; j++) biasf[j] = bfc[n0 + j * 16 + l16];

            for (int tc = 0; tc < 8; tc++) {
                // gate: all consumer epochs >= (tc+1)*64 — wave0 polls, then
                // __syncthreads broadcasts
                const unsigned need = (unsigned)((tc + 1) * 64);
                if (wv == 0) {
                    unsigned* p0 = bar + (size_t)lane * FSTR;
                    unsigned* p1 = bar + (size_t)(64 + lane) * FSTR;
                    bool d0 = false, d1 = false;
                    while (true) {
                        if (!d0) d0 = (__hip_atomic_load(p0, __ATOMIC_RELAXED,
                                           __HIP_MEMORY_SCOPE_AGENT) >= need);
                        if (!d1) d1 = (__hip_atomic_load(p1, __ATOMIC_RELAXED,
                                           __HIP_MEMORY_SCOPE_AGENT) >= need);
                        if (__all(d0 && d1)) break;
                        __builtin_amdgcn_s_sleep(8);
                    }
                    asm volatile("" ::: "memory");
                    __builtin_amdgcn_sched_barrier(0);
                }
                __syncthreads();

                const int m0 = fb * SEQ + tc * 64;

                floatx4 acc[4][4];
#pragma unroll
                for (int i = 0; i < 4; i++)
#pragma unroll
                    for (int j = 0; j < 4; j++) acc[i][j] = (floatx4)(0.0f);

                const __hip_bfloat16* arow[4];
#pragma unroll
                for (int i = 0; i < 4; i++)
                    arow[i] = hs + (size_t)(m0 + i * 16 + l16) * HD + quad * 8;

                for (int k0 = 0; k0 < HD; k0 += 32) {
                    shortx8 a[4], b[4];
#pragma unroll
                    for (int i = 0; i < 4; i++) a[i] = *(const shortx8*)(arow[i] + k0);
#pragma unroll
                    for (int j = 0; j < 4; j++) b[j] = *(const shortx8*)(brow[j] + k0);
#pragma unroll
                    for (int i = 0; i < 4; i++)
#pragma unroll
                        for (int j = 0; j < 4; j++)
                            acc[i][j] = MFMA16(a[i], b[j], acc[i][j]);
                }

#pragma unroll
                for (int j = 0; j < 4; j++) {
                    const int n = n0 + j * 16 + l16;
#pragma unroll
                    for (int i = 0; i < 4; i++) {
#pragma unroll
                        for (int r = 0; r < 4; r++) {
                            const int row = m0 + i * 16 + quad * 4 + r;
                            out[(size_t)row * 1024 + n] = acc[i][j][r] + biasf[j];
                        }
                    }
                }
            }
        }
        return;
    }

    // ========================= CONSUMER =========================
    const int wm = wv & 1;           // batch-half tile
    const int wk = wv >> 1;          // K-half

    shortx8 Bfrag[2][16];
#pragma unroll
    for (int ct = 0; ct < 2; ct++) {
        const int lc = ct * 16 + l16;
        const int jj = lc >> 2, g = lc & 3;
        const __hip_bfloat16* wr =
            Wb + (size_t)g * WG_ELEMS + (size_t)(blk * 8 + jj) * ZD + wk * 512 + quad * 8;
#pragma unroll
        for (int ks = 0; ks < 16; ks++)
            Bfrag[ct][ks] = *(const shortx8*)(wr + ks * 32);
    }

    const int pjj = tid & 7;
    const int pb  = tid >> 3;
    const int pj  = blk * 8 + pjj;
    float creg = c_ws[blk * 256 + tid];

    // prologue: wait for Gx rows of t=0 (mt 0) — wave0 polls, sync broadcasts
    if (wv == 0) {
        while (__hip_atomic_load(gcnt, __ATOMIC_RELAXED,
                                 __HIP_MEMORY_SCOPE_AGENT) < 64)
            __builtin_amdgcn_s_sleep(1);
        asm volatile("" ::: "memory");
        __builtin_amdgcn_sched_barrier(0);
    }
    __syncthreads();

    unsigned short gxr0, gxr1, gxr2, gxr3;
    {
        const __hip_bfloat16* gx = Gx + (size_t)pb * NG + pj;
        gxr0 = *(const unsigned short*)(gx + 0 * HD);
        gxr1 = *(const unsigned short*)(gx + 1 * HD);
        gxr2 = *(const unsigned short*)(gx + 2 * HD);
        gxr3 = *(const unsigned short*)(gx + 3 * HD);
    }
    int mt_ok = 0;

    // this wave's flag slot to watch: source blocks [wk*64, wk*64+64)
    unsigned* mywatch = bar + (size_t)(wk * 64 + lane) * FSTR;

    for (int tt = 0; tt < T; tt++) {
        const int t = tt;
        const __hip_bfloat16* hb;
        size_t rstride;
        if (t == 0) { hb = hzero; rstride = HD; }
        else        { hb = hs + (size_t)(t - 1) * HD; rstride = (size_t)SEQ * HD; }

        // gx prefetch for tt+1 (gcnt-gated; issues before the flag poll so
        // the loads complete under the spin)
        unsigned short ngxr0 = 0, ngxr1 = 0, ngxr2 = 0, ngxr3 = 0;
        if (tt + 1 < T) {
            const int mtn = (tt + 1) >> 1;
            if (mtn > mt_ok) {
                while (__hip_atomic_load(gcnt + (size_t)mtn * FSTR, __ATOMIC_RELAXED,
                                         __HIP_MEMORY_SCOPE_AGENT) < 64)
                    __builtin_amdgcn_s_sleep(1);
                mt_ok = mtn;
                asm volatile("" ::: "memory");
                __builtin_amdgcn_sched_barrier(0);
            }
            const __hip_bfloat16* gx1 = Gx + ((size_t)(tt + 1) * BATCH + pb) * NG + pj;
            ngxr0 = *(const unsigned short*)(gx1 + 0 * HD);
            ngxr1 = *(const unsigned short*)(gx1 + 1 * HD);
            ngxr2 = *(const unsigned short*)(gx1 + 2 * HD);
            ngxr3 = *(const unsigned short*)(gx1 + 3 * HD);
        }

        // per-wave half-barrier: wait for this wave's 64 source blocks to
        // have published epoch >= tt (h[tt-1] drained to IF). Divergent
        // while = sticky per-lane exit; wave proceeds when all lanes pass.
        if (tt > 0) {
            while (__hip_atomic_load(mywatch, __ATOMIC_RELAXED,
                                     __HIP_MEMORY_SCOPE_AGENT) < (unsigned)tt)
                __builtin_amdgcn_s_sleep(1);
            asm volatile("" ::: "memory");
            __builtin_amdgcn_sched_barrier(0);
        }

        // h @ Wh^T : one A-frag stream feeds BOTH col-tile chains
        const __hip_bfloat16* arow =
            hb + (size_t)(wm * 16 + l16) * rstride + wk * 512 + quad * 8;
        floatx4 acc0 = (floatx4)(0.0f), acc1 = (floatx4)(0.0f);
#pragma unroll
        for (int ks = 0; ks < 16; ks++) {
            shortx8 av = *(const shortx8*)(arow + ks * 32);
            acc0 = MFMA16(av, Bfrag[0][ks], acc0);
            acc1 = MFMA16(av, Bfrag[1][ks], acc1);
        }

        // acc -> LDS [wk][col][b], stride 36 floats (16B-aligned)
        {
            const int b0 = wm * 16 + quad * 4;
            *(floatx4*)(accf + wk * 1168 + (l16)      * 36 + b0) = acc0;
            *(floatx4*)(accf + wk * 1168 + (16 + l16) * 36 + b0) = acc1;
        }
        __syncthreads();   // (A) panels complete

        // pointwise for (pb, pjj); c lives in a register across the launch
        {
            const int i0 = (pjj * 4 + 0) * 36 + pb;
            const int i1 = (pjj * 4 + 1) * 36 + pb;
            const int i2 = (pjj * 4 + 2) * 36 + pb;
            const int i3 = (pjj * 4 + 3) * 36 + pb;
            const float fp = accf[i0] + accf[1168 + i0] + bf2f(gxr0);
            const float ip = accf[i1] + accf[1168 + i1] + bf2f(gxr1);
            const float cp = accf[i2] + accf[1168 + i2] + bf2f(gxr2);
            const float op = accf[i3] + accf[1168 + i3] + bf2f(gxr3);
            const float fg = sigmoidf_(fp);
            const float ig = sigmoidf_(ip);
            const float cg = tanhf_(cp);
            const float og = sigmoidf_(op);
            creg = ig * cg + fg * creg;
            const float hnew = og * tanhf_(creg);

            // packed-u32 relaxed agent store (sc1 => coherence-point visible)
            const unsigned my = (unsigned)(unsigned short)bf16s(hnew);
            const unsigned nb = (unsigned)__shfl_xor((int)my, 1);
            if ((tid & 1) == 0) {
                unsigned* dst = (unsigned*)(hs + ((size_t)pb * SEQ + t) * HD + pj);
                const unsigned packed = my | (nb << 16);
                __hip_atomic_store(dst, packed, __ATOMIC_RELAXED,
                                   __HIP_MEMORY_SCOPE_AGENT);
            }
        }

        __syncthreads();   // (B) accf reads done; each wave's vmcnt(0) drains
                           //     its sc1 h stores to the coherence point
        // publish arrival AFTER the drain barrier (ordering argument = v5);
        // published every step incl. the last (FC workers gate on epoch T)
        if (wv == 0 && lane == 0) {
            __hip_atomic_store(bar + (size_t)blk * FSTR, (unsigned)(tt + 1),
                               __ATOMIC_RELAXED, __HIP_MEMORY_SCOPE_AGENT);
        }

        gxr0 = ngxr0; gxr1 = ngxr1; gxr2 = ngxr2; gxr3 = ngxr3;
    }

    c_ws[blk * 256 + tid] = creg;
}

// ---------------------------------------------------------------------------
// Kernel 3 (FALLBACK only): out[r][n] = sum_k hs[r][k]*Wfc[n][k] + bfc[n]
// ---------------------------------------------------------------------------
__global__ __launch_bounds__(256) void gemm_fc(
    const __hip_bfloat16* __restrict__ hs,
    const __hip_bfloat16* __restrict__ Wfcb,
    const float* __restrict__ bfc,
    float* __restrict__ out)
{
    const int wave = (blockIdx.x << 2) + (threadIdx.x >> 6);
    const int mt = wave >> 4;
    const int nt = wave & 15;
    const int lane = threadIdx.x & 63;
    const int quad = lane >> 4;
    const int l16  = lane & 15;
    const int m0 = mt << 6;
    const int n0 = nt << 6;

    floatx4 acc[4][4];
#pragma unroll
    for (int i = 0; i < 4; i++)
#pragma unroll
        for (int j = 0; j < 4; j++) acc[i][j] = (floatx4)(0.0f);

    const __hip_bfloat16* arow[4];
    const __hip_bfloat16* brow[4];
#pragma unroll
    for (int i = 0; i < 4; i++)
        arow[i] = hs + (size_t)(m0 + i * 16 + l16) * HD + quad * 8;
#pragma unroll
    for (int j = 0; j < 4; j++)
        brow[j] = Wfcb + (size_t)(n0 + j * 16 + l16) * HD + quad * 8;

    for (int k0 = 0; k0 < HD; k0 += 32) {
        shortx8 a[4], b[4];
#pragma unroll
        for (int i = 0; i < 4; i++) a[i] = *(const shortx8*)(arow[i] + k0);
#pragma unroll
        for (int j = 0; j < 4; j++) b[j] = *(const shortx8*)(brow[j] + k0);
#pragma unroll
        for (int i = 0; i < 4; i++)
#pragma unroll
            for (int j = 0; j < 4; j++)
                acc[i][j] = MFMA16(a[i], b[j], acc[i][j]);
    }

#pragma unroll
    for (int j = 0; j < 4; j++) {
        const int n = n0 + j * 16 + l16;
        const float bias = bfc[n];
#pragma unroll
        for (int i = 0; i < 4; i++) {
#pragma unroll
            for (int r = 0; r < 4; r++) {
                const int row = m0 + i * 16 + quad * 4 + r;
                out[(size_t)row * 1024 + n] = acc[i][j][r] + bias;
            }
        }
    }
}

// ---------------------------------------------------------------------------
extern "C" void kernel_launch(void* const* d_in, const int* in_sizes, int n_in,
                              void* d_out, int out_size, void* d_ws, size_t ws_size,
                              hipStream_t stream) {
    const float* x   = (const float*)d_in[0];
    const float* Wf  = (const float*)d_in[1];
    const float* bf_ = (const float*)d_in[2];
    const float* Wi  = (const float*)d_in[3];
    const float* bi_ = (const float*)d_in[4];
    const float* Wc  = (const float*)d_in[5];
    const float* bc_ = (const float*)d_in[6];
    const float* Wo  = (const float*)d_in[7];
    const float* bo_ = (const float*)d_in[8];
    const float* Wfc = (const float*)d_in[9];
    const float* bfc = (const float*)d_in[10];
    float* out = (float*)d_out;

    // ---- ws layout (bytes) ----
    char* ws = (char*)d_ws;
    const size_t WB_OFF  = 0;                                          // 16 MiB
    const size_t WFC_OFF = (size_t)4 * WG_ELEMS * 2;                   // +2 MiB
    const size_t HS_OFF  = WFC_OFF + (size_t)HD * HD * 2;              // +32 MiB
    const size_t ST_OFF  = HS_OFF + (size_t)BATCH * SEQ * HD * 2;
    const size_t HZ_BYTES  = (size_t)BATCH * HD * 2;                   // 64 KiB
    const size_t C_BYTES   = (size_t)PBLK * 256 * 4;                   // 128 KiB
    const size_t BAR_BYTES = (size_t)(128 + 256) * FSTR * 4;           // ~102 KiB
    const size_t ST_BYTES  = HZ_BYTES + C_BYTES + BAR_BYTES;
    const size_t GX_OFF  = ST_OFF + ST_BYTES;

    __hip_bfloat16* Wb    = (__hip_bfloat16*)(ws + WB_OFF);
    __hip_bfloat16* Wfcb  = (__hip_bfloat16*)(ws + WFC_OFF);
    __hip_bfloat16* hs    = (__hip_bfloat16*)(ws + HS_OFF);
    __hip_bfloat16* hzero = (__hip_bfloat16*)(ws + ST_OFF);
    float*          cbuf  = (float*)(ws + ST_OFF + HZ_BYTES);
    unsigned*       bar   = (unsigned*)(ws + ST_OFF + HZ_BYTES + C_BYTES);
    __hip_bfloat16* Gx    = (__hip_bfloat16*)(ws + GX_OFF);

    // fast path needs the full Gx array (128 MiB)
    const size_t GX_FULL = (size_t)SEQ * BATCH * NG * 2;
    const int persist = (GX_OFF + GX_FULL <= ws_size);
    int T_CHUNK = 1;
    if (!persist) {
        const size_t GX_STEP = (size_t)BATCH * NG * 2;   // 256 KiB per step
        const int fopts[3] = {8, 2, 1};
        for (int i = 0; i < 3; i++) {
            if (GX_OFF + (size_t)fopts[i] * GX_STEP <= ws_size) {
                T_CHUNK = fopts[i]; break;
            }
        }
    }

    // one-time weight conversion fp32 -> bf16 (single fused launch)
    cvt_weights<<<9216, 256, 0, stream>>>(Wf, Wi, Wc, Wo, Wfc, Wb, Wfcb);

    // zero hzero, c, barrier + ready-counter state (ws poisoned every launch)
    hipMemsetAsync(ws + ST_OFF, 0, ST_BYTES, stream);

    if (persist) {
        // single launch: 128 consumer + 128 producer/FC blocks (256 CUs)
        lstm_persist<<<2 * PBLK, 256, 0, stream>>>(
            Wb, x, Gx, bf_, bi_, bc_, bo_, Wfcb, bfc, out,
            SEQ, hzero, cbuf, hs, bar);
    } else {
        for (int t0 = 0; t0 < SEQ; t0 += T_CHUNK) {
            gemm_gx<<<T_CHUNK * 8, 256, 0, stream>>>(
                x, Wb, bf_, bi_, bc_, bo_, Gx, t0);
            for (int t = t0; t < t0 + T_CHUNK; t++) {
                const __hip_bfloat16* gx_t = Gx + (size_t)(t - t0) * BATCH * NG;
                lstm_step<<<16, 256, 0, stream>>>(gx_t, t, Wb, hzero, cbuf, hs);
            }
        }
        gemm_fc<<<1024, 256, 0, stream>>>(hs, Wfcb, bfc, out);
    }
}